// Round 3
// baseline (3245.116 us; speedup 1.0000x reference)
//
#include <hip/hip_runtime.h>

#define NN 50000
#define EE 1600000

using u16 = unsigned short;
using u32 = unsigned int;

typedef float f32x4 __attribute__((ext_vector_type(4)));
typedef __bf16 bf16x8 __attribute__((ext_vector_type(8)));
typedef unsigned short u16x8 __attribute__((ext_vector_type(8)));

struct alignas(8) U16x4 { u16 a, b, c, d; };
struct PtrTab { const void* p[20]; };

// canonical fp32 weight-pad offsets
#define OW1 0
#define OB1 768
#define OG 896
#define OBB 1024
#define ORM 1152
#define ORV 1280
#define OW2 1408
#define OB2 17792
#define OCH0 17920
#define OCH1 42496
#define OCH2 54784
#define OCH3 67072
#define OCW1 79360
#define OCB1 144896
#define OCG 145152
#define OCBB 145408
#define OCRM 145664
#define OCRV 145920
#define OCW2 146176
#define OCB2 146688
#define OTOT 146690

// element offsets within d_out (dtype-independent in elements)
#define LG_OFF ((size_t)NN * 256)
#define EW_OFF ((size_t)NN * 256 + (size_t)NN * 2)

__device__ __forceinline__ float bf2f(u16 u) { return __builtin_bit_cast(float, (u32)u << 16); }
__device__ __forceinline__ float bfl(u32 u) { return __builtin_bit_cast(float, u << 16); }
__device__ __forceinline__ float bfh(u32 u) { return __builtin_bit_cast(float, u & 0xffff0000u); }
__device__ __forceinline__ u16 f2bf(float f) {
    u32 u = __builtin_bit_cast(u32, f);
    return (u16)((u + 0x7fffu + ((u >> 16) & 1u)) >> 16);
}

// Input dtype detector: flag=1 -> bf16 inputs, 0 -> fp32 inputs.
__global__ __launch_bounds__(256) void k_detect(const u16* __restrict__ f, int* __restrict__ flag) {
    __shared__ int bad;
    if (threadIdx.x == 0) bad = 0;
    __syncthreads();
    u16 u = f[threadIdx.x];
    int e = (u >> 7) & 0xFF;
    if (e >= 0x90) atomicAdd(&bad, 1);
    __syncthreads();
    if (threadIdx.x == 0) flag[0] = (bad < 16) ? 1 : 0;
}

// Convert all 20 weight arrays into canonical fp32 pad.
__global__ __launch_bounds__(256) void k_wconv(PtrTab tab, const int* __restrict__ flag,
                                               float* __restrict__ wpad) {
    const int SZ[20] = {768, 128, 128, 128, 128, 128, 16384, 128, 24576, 12288, 12288, 12288,
                        65536, 256, 256, 256, 256, 256, 512, 2};
    const int OF[20] = {OW1, OB1, OG, OBB, ORM, ORV, OW2, OB2, OCH0, OCH1, OCH2, OCH3,
                        OCW1, OCB1, OCG, OCBB, OCRM, OCRV, OCW2, OCB2};
    int a = blockIdx.x;
    int n = SZ[a];
    float* dst = wpad + OF[a];
    if (flag[0] != 0) {
        const u16* s = (const u16*)tab.p[a];
        for (int i = threadIdx.x; i < n; i += 256) dst[i] = bf2f(s[i]);
    } else {
        const float* s = (const float*)tab.p[a];
        for (int i = threadIdx.x; i < n; i += 256) dst[i] = s[i];
    }
}

// Fold PAE BN into W2 (MFMA B-frag swizzled bf16) + b2'.
__global__ __launch_bounds__(128) void k_fold(const float* __restrict__ wpad,
                                              u16* __restrict__ W2s, float* __restrict__ b2p) {
    const float* g = wpad + OG;
    const float* b = wpad + OBB;
    const float* rm = wpad + ORM;
    const float* rv = wpad + ORV;
    const float* w2 = wpad + OW2;
    const float* b2 = wpad + OB2;
    int blk = blockIdx.x, tid = threadIdx.x;
    if (blk < 32) {
        int kc = blk >> 3, jt = blk & 7;
        int lane = tid & 63, jh = tid >> 6;
        for (int jj = 0; jj < 4; jj++) {
            int j = jh * 4 + jj;
            int k = kc * 32 + (lane >> 4) * 8 + j;
            int jcol = jt * 16 + (lane & 15);
            float s = g[k] * rsqrtf(rv[k] + 1e-5f);
            W2s[((kc * 8 + jt) * 64 + lane) * 8 + j] = f2bf(s * w2[k * 128 + jcol]);
        }
    } else {
        if (tid < 128) {
            int j = tid;
            float acc = b2[j];
            for (int k = 0; k < 128; k++) {
                float s = g[k] * rsqrtf(rv[k] + 1e-5f);
                float t = b[k] - rm[k] * s;
                acc += t * w2[k * 128 + j];
            }
            b2p[j] = acc;
        }
    }
}

// features (either dtype) -> bf16 X0.
__global__ __launch_bounds__(256) void k_x0(const void* __restrict__ feat, const int* __restrict__ flag,
                                            u16* __restrict__ X0) {
    int i = blockIdx.x * 256 + threadIdx.x;
    if (flag[0] != 0) {
        ((uint4*)X0)[i] = ((const uint4*)feat)[i];
    } else {
        const float4* f = (const float4*)feat;
        float4 a = f[2 * i], b = f[2 * i + 1];
        u16x8 o;
        o[0] = f2bf(a.x); o[1] = f2bf(a.y); o[2] = f2bf(a.z); o[3] = f2bf(a.w);
        o[4] = f2bf(b.x); o[5] = f2bf(b.y); o[6] = f2bf(b.z); o[7] = f2bf(b.w);
        ((uint4*)X0)[i] = __builtin_bit_cast(uint4, o);
    }
}

// PAE: A = relu(Z@W1+b1) on VALU (fragments staged once), H = A@W2' via MFMA
// with jt-outer loop (2 live accumulators), cosine -> edge weight.
__global__ __launch_bounds__(256, 4) void k_pae(const void* __restrict__ zin, const float* __restrict__ wpad,
                                                const u16* __restrict__ W2sg, const float* __restrict__ b2p,
                                                const int* __restrict__ ei, const int* __restrict__ flag,
                                                float* __restrict__ ewf, void* __restrict__ dout,
                                                float* __restrict__ deg, int* __restrict__ cnt) {
    __shared__ __align__(16) u16 sW2[16384];
    __shared__ float sW1[6 * 128];
    __shared__ float sB1[128];
    __shared__ float sB2[128];
    int tid = threadIdx.x;
    for (int i = tid; i < 8192; i += 256) ((u32*)sW2)[i] = ((const u32*)W2sg)[i];
    for (int i = tid; i < 768; i += 256) sW1[i] = wpad[OW1 + i];
    if (tid < 128) { sB1[tid] = wpad[OB1 + tid]; sB2[tid] = b2p[tid]; }
    __syncthreads();

    bool isbf = flag[0] != 0;
    int wv = __builtin_amdgcn_readfirstlane(tid >> 6);
    int lane = tid & 63;
    int quad = lane >> 4, lrow = lane & 15, jc = lane & 15;
    int gw = blockIdx.x * 4 + wv;
    const int ngroups = EE / 16;

    for (int gidx = gw; gidx < ngroups; gidx += gridDim.x * 4) {
        int e0 = gidx * 16;
        float z1[6], z2[6];
        if (isbf) {
            const u32* zp = (const u32*)((const u16*)zin + (size_t)(e0 + lrow) * 12);
            u32 u0 = zp[0], u1 = zp[1], u2 = zp[2], u3 = zp[3], u4 = zp[4], u5 = zp[5];
            z1[0] = bfl(u0); z1[1] = bfh(u0); z1[2] = bfl(u1); z1[3] = bfh(u1); z1[4] = bfl(u2); z1[5] = bfh(u2);
            z2[0] = bfl(u3); z2[1] = bfh(u3); z2[2] = bfl(u4); z2[3] = bfh(u4); z2[4] = bfl(u5); z2[5] = bfh(u5);
        } else {
            const float4* zp = (const float4*)((const float*)zin + (size_t)(e0 + lrow) * 12);
            float4 p0 = zp[0], p1 = zp[1], p2 = zp[2];
            z1[0] = p0.x; z1[1] = p0.y; z1[2] = p0.z; z1[3] = p0.w; z1[4] = p1.x; z1[5] = p1.y;
            z2[0] = p1.z; z2[1] = p1.w; z2[2] = p2.x; z2[3] = p2.y; z2[4] = p2.z; z2[5] = p2.w;
        }

        // Stage A fragments for all 4 kc chunks (32 VGPRs total)
        bf16x8 a1f[4], a2f[4];
#pragma unroll
        for (int kc = 0; kc < 4; kc++) {
            u16x8 a1u, a2u;
            int kbase = kc * 32 + quad * 8;
#pragma unroll
            for (int j = 0; j < 8; j++) {
                int k = kbase + j;
                float s1 = sB1[k], s2 = s1;
#pragma unroll
                for (int m = 0; m < 6; m++) {
                    float wm = sW1[m * 128 + k];
                    s1 = fmaf(z1[m], wm, s1);
                    s2 = fmaf(z2[m], wm, s2);
                }
                a1u[j] = f2bf(fmaxf(s1, 0.f));
                a2u[j] = f2bf(fmaxf(s2, 0.f));
            }
            a1f[kc] = __builtin_bit_cast(bf16x8, a1u);
            a2f[kc] = __builtin_bit_cast(bf16x8, a2u);
        }

        float num[4] = {0, 0, 0, 0}, q1[4] = {0, 0, 0, 0}, q2[4] = {0, 0, 0, 0};
        // jt-outer: only 2 f32x4 accumulators live at a time
#pragma unroll
        for (int jt = 0; jt < 8; jt++) {
            f32x4 acc1 = {0.f, 0.f, 0.f, 0.f}, acc2 = {0.f, 0.f, 0.f, 0.f};
#pragma unroll
            for (int kc = 0; kc < 4; kc++) {
                bf16x8 bb = *reinterpret_cast<const bf16x8*>(&sW2[((kc * 8 + jt) * 64 + lane) * 8]);
                acc1 = __builtin_amdgcn_mfma_f32_16x16x32_bf16(a1f[kc], bb, acc1, 0, 0, 0);
                acc2 = __builtin_amdgcn_mfma_f32_16x16x32_bf16(a2f[kc], bb, acc2, 0, 0, 0);
            }
            float bbias = sB2[jt * 16 + jc];
#pragma unroll
            for (int r = 0; r < 4; r++) {
                float h1 = acc1[r] + bbias;
                float h2 = acc2[r] + bbias;
                num[r] = fmaf(h1, h2, num[r]);
                q1[r] = fmaf(h1, h1, q1[r]);
                q2[r] = fmaf(h2, h2, q2[r]);
            }
        }
#pragma unroll
        for (int off = 1; off < 16; off <<= 1) {
#pragma unroll
            for (int r = 0; r < 4; r++) {
                num[r] += __shfl_xor(num[r], off);
                q1[r] += __shfl_xor(q1[r], off);
                q2[r] += __shfl_xor(q2[r], off);
            }
        }
        if (jc == 0) {
#pragma unroll
            for (int r = 0; r < 4; r++) {
                int e = e0 + quad * 4 + r;
                float den = fmaxf(sqrtf(q1[r]) * sqrtf(q2[r]), 1e-8f);
                float wgt = (num[r] / den + 1.f) * 0.5f;
                if (!(wgt == wgt)) wgt = 0.5f;  // NaN guard: makes failures localizable
                ewf[e] = wgt;
                if (isbf) ((u16*)dout)[EW_OFF + e] = f2bf(wgt);
                else ((float*)dout)[EW_OFF + e] = wgt;
                int row = ei[e];
                atomicAdd(deg + row, wgt);
                atomicAdd(cnt + row, 1);
            }
        }
    }
}

// Exclusive scan of cnt -> offs; fused dis = rsqrt(deg).
__global__ __launch_bounds__(1024) void k_scan(const int* __restrict__ cnt, const float* __restrict__ deg,
                                               int* __restrict__ offs, float* __restrict__ dis) {
    __shared__ int wsum[16];
    __shared__ int carry;
    int tid = threadIdx.x;
    int wv = tid >> 6, lane = tid & 63;
    if (tid == 0) carry = 0;
    __syncthreads();
    for (int c = 0; c < 49; c++) {
        int i = c * 1024 + tid;
        int v = (i < NN) ? cnt[i] : 0;
        if (i < NN) {
            float d = deg[i];
            dis[i] = d > 0.f ? rsqrtf(d) : 0.f;
        }
        int x = v;
#pragma unroll
        for (int off = 1; off < 64; off <<= 1) {
            int t = __shfl_up(x, off);
            if (lane >= off) x += t;
        }
        if (lane == 63) wsum[wv] = x;
        __syncthreads();
        if (tid < 16) {
            int s = wsum[tid];
#pragma unroll
            for (int off = 1; off < 16; off <<= 1) {
                int t = __shfl_up(s, off, 16);
                if (tid >= off) s += t;
            }
            wsum[tid] = s;
        }
        __syncthreads();
        int base = carry + (wv > 0 ? wsum[wv - 1] : 0);
        if (i < NN) offs[i] = base + x - v;
        __syncthreads();
        if (tid == 0) carry += wsum[15];
        __syncthreads();
    }
    if (tid == 0) offs[NN] = carry;
}

// CSR scatter.
__global__ __launch_bounds__(256) void k_csr(const int* __restrict__ ei, const float* __restrict__ ewf,
                                             const float* __restrict__ dis, const int* __restrict__ offs,
                                             int* __restrict__ cursor, int* __restrict__ csr_col,
                                             float* __restrict__ csr_norm) {
    int e = blockIdx.x * 256 + threadIdx.x;
    int r = ei[e], c = ei[EE + e];
    float wgt = ewf[e];
    int pos = offs[r] + atomicAdd(cursor + r, 1);
    csr_col[pos] = c;
    csr_norm[pos] = -dis[r] * wgt * dis[c];
}

// Propagation over bf16 node features, fp32 accumulate. One wave per node,
// 4 edges per iteration: 16 lanes per edge, full feature row per 16-lane group.
template <int F>
__global__ __launch_bounds__(256) void k_prop(const u16* __restrict__ src, const int* __restrict__ csr_col,
                                              const float* __restrict__ csr_norm, const int* __restrict__ offs,
                                              u16* __restrict__ out, const u16* __restrict__ base,
                                              float alpha, float beta) {
    int lane = threadIdx.x & 63;
    int wv = threadIdx.x >> 6;
    int node = blockIdx.x * 4 + wv;
    int s = offs[node], e = offs[node + 1];
    int sub = lane >> 4;   // which of 4 edges this lane group handles
    int fl = lane & 15;    // position within the feature row

    if (F == 128) {
        const uint4* sv = (const uint4*)src;  // row = 16 uint4 (128 bf16)
        float a[8] = {0, 0, 0, 0, 0, 0, 0, 0};
        int p = s;
        for (; p + 3 < e; p += 4) {
            int c = csr_col[p + sub];
            float w = csr_norm[p + sub];
            uint4 v = sv[(size_t)c * 16 + fl];
            a[0] = fmaf(w, bfl(v.x), a[0]); a[1] = fmaf(w, bfh(v.x), a[1]);
            a[2] = fmaf(w, bfl(v.y), a[2]); a[3] = fmaf(w, bfh(v.y), a[3]);
            a[4] = fmaf(w, bfl(v.z), a[4]); a[5] = fmaf(w, bfh(v.z), a[5]);
            a[6] = fmaf(w, bfl(v.w), a[6]); a[7] = fmaf(w, bfh(v.w), a[7]);
        }
#pragma unroll
        for (int i = 0; i < 8; i++) {
            a[i] += __shfl_xor(a[i], 16);
            a[i] += __shfl_xor(a[i], 32);
        }
        if (sub == 0) {
            for (; p < e; p++) {
                int c = csr_col[p];
                float w = csr_norm[p];
                uint4 v = sv[(size_t)c * 16 + fl];
                a[0] = fmaf(w, bfl(v.x), a[0]); a[1] = fmaf(w, bfh(v.x), a[1]);
                a[2] = fmaf(w, bfl(v.y), a[2]); a[3] = fmaf(w, bfh(v.y), a[3]);
                a[4] = fmaf(w, bfl(v.z), a[4]); a[5] = fmaf(w, bfh(v.z), a[5]);
                a[6] = fmaf(w, bfl(v.w), a[6]); a[7] = fmaf(w, bfh(v.w), a[7]);
            }
            float o[8];
#pragma unroll
            for (int i = 0; i < 8; i++) o[i] = alpha * a[i];
            if (beta != 0.f) {
                uint4 bv = ((const uint4*)base)[(size_t)node * 16 + fl];
                o[0] = fmaf(beta, bfl(bv.x), o[0]); o[1] = fmaf(beta, bfh(bv.x), o[1]);
                o[2] = fmaf(beta, bfl(bv.y), o[2]); o[3] = fmaf(beta, bfh(bv.y), o[3]);
                o[4] = fmaf(beta, bfl(bv.z), o[4]); o[5] = fmaf(beta, bfh(bv.z), o[5]);
                o[6] = fmaf(beta, bfl(bv.w), o[6]); o[7] = fmaf(beta, bfh(bv.w), o[7]);
            }
            uint4 ov;
            ov.x = (u32)f2bf(o[0]) | ((u32)f2bf(o[1]) << 16);
            ov.y = (u32)f2bf(o[2]) | ((u32)f2bf(o[3]) << 16);
            ov.z = (u32)f2bf(o[4]) | ((u32)f2bf(o[5]) << 16);
            ov.w = (u32)f2bf(o[6]) | ((u32)f2bf(o[7]) << 16);
            ((uint4*)out)[(size_t)node * 16 + fl] = ov;
        }
    } else {
        const uint2* sv = (const uint2*)src;  // row = 16 uint2 (64 bf16)
        float a[4] = {0, 0, 0, 0};
        int p = s;
        for (; p + 3 < e; p += 4) {
            int c = csr_col[p + sub];
            float w = csr_norm[p + sub];
            uint2 v = sv[(size_t)c * 16 + fl];
            a[0] = fmaf(w, bfl(v.x), a[0]); a[1] = fmaf(w, bfh(v.x), a[1]);
            a[2] = fmaf(w, bfl(v.y), a[2]); a[3] = fmaf(w, bfh(v.y), a[3]);
        }
#pragma unroll
        for (int i = 0; i < 4; i++) {
            a[i] += __shfl_xor(a[i], 16);
            a[i] += __shfl_xor(a[i], 32);
        }
        if (sub == 0) {
            for (; p < e; p++) {
                int c = csr_col[p];
                float w = csr_norm[p];
                uint2 v = sv[(size_t)c * 16 + fl];
                a[0] = fmaf(w, bfl(v.x), a[0]); a[1] = fmaf(w, bfh(v.x), a[1]);
                a[2] = fmaf(w, bfl(v.y), a[2]); a[3] = fmaf(w, bfh(v.y), a[3]);
            }
            float o[4];
#pragma unroll
            for (int i = 0; i < 4; i++) o[i] = alpha * a[i];
            if (beta != 0.f) {
                uint2 bv = ((const uint2*)base)[(size_t)node * 16 + fl];
                o[0] = fmaf(beta, bfl(bv.x), o[0]); o[1] = fmaf(beta, bfh(bv.x), o[1]);
                o[2] = fmaf(beta, bfl(bv.y), o[2]); o[3] = fmaf(beta, bfh(bv.y), o[3]);
            }
            uint2 ov;
            ov.x = (u32)f2bf(o[0]) | ((u32)f2bf(o[1]) << 16);
            ov.y = (u32)f2bf(o[2]) | ((u32)f2bf(o[3]) << 16);
            ((uint2*)out)[(size_t)node * 16 + fl] = ov;
        }
    }
}

// ChebConv mix -> bf16 h + jk slice (out dtype).
template <int F>
__global__ __launch_bounds__(256) void k_gemm(const u16* __restrict__ X0, const u16* __restrict__ X1,
                                              const u16* __restrict__ X2, const float* __restrict__ Wg,
                                              u16* __restrict__ Hout, void* __restrict__ jk, int jkoff,
                                              const int* __restrict__ flag) {
    __shared__ u16 sW[3 * 64 * (F + 4)];
    int tid = threadIdx.x;
    for (int idx = tid; idx < 3 * F * 64; idx += 256) {
        int j = idx & 63;
        int rest = idx >> 6;
        int k = rest % F;
        int p = rest / F;
        sW[(p * 64 + j) * (F + 4) + k] = f2bf(Wg[(p * F + k) * 64 + j]);
    }
    __syncthreads();
    bool isbf = flag[0] != 0;
    int wv = __builtin_amdgcn_readfirstlane(tid >> 6);
    int lane = tid & 63;
    int nbase = blockIdx.x * 32 + wv * 8;
    float acc[8] = {0, 0, 0, 0, 0, 0, 0, 0};
    const u16* Xs[3] = {X0, X1, X2};
    for (int p = 0; p < 3; p++) {
        const u16* Xp = Xs[p];
        const u16* wrow = &sW[(p * 64 + lane) * (F + 4)];
        const u16* rp[8];
#pragma unroll
        for (int i = 0; i < 8; i++) {
            int n = nbase + i;
            if (n > NN - 1) n = NN - 1;
            rp[i] = Xp + (size_t)n * F;
        }
        for (int k = 0; k < F; k += 4) {
            U16x4 w4 = *(const U16x4*)&wrow[k];
            float w0 = bf2f(w4.a), w1 = bf2f(w4.b), w2 = bf2f(w4.c), w3 = bf2f(w4.d);
#pragma unroll
            for (int i = 0; i < 8; i++) {
                U16x4 xv = *(const U16x4*)(rp[i] + k);
                acc[i] = fmaf(bf2f(xv.a), w0, acc[i]);
                acc[i] = fmaf(bf2f(xv.b), w1, acc[i]);
                acc[i] = fmaf(bf2f(xv.c), w2, acc[i]);
                acc[i] = fmaf(bf2f(xv.d), w3, acc[i]);
            }
        }
    }
#pragma unroll
    for (int i = 0; i < 8; i++) {
        int n = nbase + i;
        if (n < NN) {
            float v = fmaxf(acc[i], 0.f);
            Hout[(size_t)n * 64 + lane] = f2bf(v);
            if (isbf) ((u16*)jk)[(size_t)n * 256 + jkoff + lane] = f2bf(v);
            else ((float*)jk)[(size_t)n * 256 + jkoff + lane] = v;
        }
    }
}

// Classifier stage 1 -> internal bf16 z.
__global__ __launch_bounds__(256) void k_cls1(const u16* __restrict__ h0, const u16* __restrict__ h1,
                                              const u16* __restrict__ h2, const u16* __restrict__ h3,
                                              const float* __restrict__ wpad, u16* __restrict__ zout) {
    __shared__ u16 sW[64 * 260];
    int tid = threadIdx.x;
    int jch = blockIdx.y;
    const float* w1 = wpad + OCW1;
    for (int idx = tid; idx < 64 * 256; idx += 256) {
        int j = idx & 63, k = idx >> 6;
        sW[j * 260 + k] = f2bf(w1[k * 256 + jch * 64 + j]);
    }
    __syncthreads();
    int wv = __builtin_amdgcn_readfirstlane(tid >> 6);
    int lane = tid & 63;
    int nbase = blockIdx.x * 32 + wv * 8;
    float acc[8] = {0, 0, 0, 0, 0, 0, 0, 0};
    const u16* hs[4] = {h0, h1, h2, h3};
    const u16* wrow = &sW[lane * 260];
    for (int l = 0; l < 4; l++) {
        const u16* hb = hs[l];
        const u16* rp[8];
#pragma unroll
        for (int i = 0; i < 8; i++) {
            int n = nbase + i;
            if (n > NN - 1) n = NN - 1;
            rp[i] = hb + (size_t)n * 64;
        }
        for (int kk = 0; kk < 64; kk += 4) {
            U16x4 w4 = *(const U16x4*)&wrow[l * 64 + kk];
            float w0 = bf2f(w4.a), w1f = bf2f(w4.b), w2f = bf2f(w4.c), w3f = bf2f(w4.d);
#pragma unroll
            for (int i = 0; i < 8; i++) {
                U16x4 xv = *(const U16x4*)(rp[i] + kk);
                acc[i] = fmaf(bf2f(xv.a), w0, acc[i]);
                acc[i] = fmaf(bf2f(xv.b), w1f, acc[i]);
                acc[i] = fmaf(bf2f(xv.c), w2f, acc[i]);
                acc[i] = fmaf(bf2f(xv.d), w3f, acc[i]);
            }
        }
    }
    int j = jch * 64 + lane;
    float bb1 = wpad[OCB1 + j];
    float s = wpad[OCG + j] * rsqrtf(wpad[OCRV + j] + 1e-5f);
    float t = wpad[OCBB + j] - wpad[OCRM + j] * s;
#pragma unroll
    for (int i = 0; i < 8; i++) {
        int n = nbase + i;
        if (n < NN) {
            float v = fmaxf(acc[i] + bb1, 0.f) * s + t;
            zout[(size_t)n * 256 + j] = f2bf(v);
        }
    }
}

// Classifier stage 2: logit into d_out at LG_OFF (out dtype).
__global__ __launch_bounds__(256) void k_cls2(const u16* __restrict__ z, const float* __restrict__ wpad,
                                              const int* __restrict__ flag, void* __restrict__ dout) {
    __shared__ float sw2[512];
    __shared__ float sb2[2];
    int tid = threadIdx.x;
    for (int i = tid; i < 512; i += 256) sw2[i] = wpad[OCW2 + i];
    if (tid < 2) sb2[tid] = wpad[OCB2 + tid];
    __syncthreads();
    bool isbf = flag[0] != 0;
    int wv = __builtin_amdgcn_readfirstlane(tid >> 6);
    int lane = tid & 63;
    int node = blockIdx.x * 4 + wv;
    U16x4 zv = *(const U16x4*)(z + (size_t)node * 256 + lane * 4);
    float zf[4] = {bf2f(zv.a), bf2f(zv.b), bf2f(zv.c), bf2f(zv.d)};
    float p0 = 0.f, p1 = 0.f;
#pragma unroll
    for (int m = 0; m < 4; m++) {
        int k = lane * 4 + m;
        p0 = fmaf(zf[m], sw2[k * 2 + 0], p0);
        p1 = fmaf(zf[m], sw2[k * 2 + 1], p1);
    }
#pragma unroll
    for (int off = 1; off < 64; off <<= 1) {
        p0 += __shfl_xor(p0, off);
        p1 += __shfl_xor(p1, off);
    }
    if (lane == 0) {
        float l0 = p0 + sb2[0], l1 = p1 + sb2[1];
        if (isbf) {
            u32 pack = (u32)f2bf(l0) | ((u32)f2bf(l1) << 16);
            *(u32*)((u16*)dout + LG_OFF + (size_t)node * 2) = pack;
        } else {
            float2 o = {l0, l1};
            *(float2*)((float*)dout + LG_OFF + (size_t)node * 2) = o;
        }
    }
}

extern "C" void kernel_launch(void* const* d_in, const int* in_sizes, int n_in,
                              void* d_out, int out_size, void* d_ws, size_t ws_size,
                              hipStream_t stream) {
    const void* features = d_in[0];
    const int* ei = (const int*)d_in[1];
    const void* zin = d_in[2];

    char* w = (char*)d_ws;
    auto alloc = [&](size_t bytes) -> void* {
        void* p = (void*)w;
        w += (bytes + 255) & ~(size_t)255;
        return p;
    };
    u16* X0 = (u16*)alloc((size_t)NN * 128 * 2);
    u16* Tx1 = (u16*)alloc((size_t)NN * 128 * 2);
    u16* Tx2 = (u16*)alloc((size_t)NN * 128 * 2);
    u16* h0 = (u16*)alloc((size_t)NN * 64 * 2);
    u16* h1 = (u16*)alloc((size_t)NN * 64 * 2);
    u16* h2 = (u16*)alloc((size_t)NN * 64 * 2);
    u16* h3 = (u16*)alloc((size_t)NN * 64 * 2);
    float* ewf = (float*)alloc((size_t)EE * 4);
    int* csr_col = (int*)alloc((size_t)EE * 4);
    float* csr_norm = (float*)alloc((size_t)EE * 4);
    float* deg = (float*)alloc((size_t)NN * 4);
    int* cnt = (int*)alloc((size_t)NN * 4);
    int* cursor = (int*)alloc((size_t)NN * 4);
    float* dis = (float*)alloc((size_t)NN * 4);
    int* offs = (int*)alloc((size_t)(NN + 1) * 4);
    u16* W2s = (u16*)alloc((size_t)16384 * 2);
    float* b2p = (float*)alloc((size_t)128 * 4);
    float* wpad = (float*)alloc((size_t)OTOT * 4);
    int* flag = (int*)alloc(256);
    u16* z = X0;  // reuses X0+Tx1 region (25.6MB), free after layer-3 gemm

    hipMemsetAsync(deg, 0, (size_t)((char*)dis - (char*)deg), stream);

    PtrTab tab;
    for (int i = 0; i < 20; i++) tab.p[i] = d_in[3 + i];

    k_detect<<<1, 256, 0, stream>>>((const u16*)features, flag);
    k_wconv<<<20, 256, 0, stream>>>(tab, flag, wpad);
    k_fold<<<33, 128, 0, stream>>>(wpad, W2s, b2p);
    k_x0<<<3125, 256, 0, stream>>>(features, flag, X0);
    k_pae<<<1024, 256, 0, stream>>>(zin, wpad, W2s, b2p, ei, flag, ewf, d_out, deg, cnt);
    k_scan<<<1, 1024, 0, stream>>>(cnt, deg, offs, dis);
    k_csr<<<EE / 256, 256, 0, stream>>>(ei, ewf, dis, offs, cursor, csr_col, csr_norm);

    // layer 0 (F=128)
    k_prop<128><<<12500, 256, 0, stream>>>(X0, csr_col, csr_norm, offs, Tx1, nullptr, 1.f, 0.f);
    k_prop<128><<<12500, 256, 0, stream>>>(Tx1, csr_col, csr_norm, offs, Tx2, X0, 2.f, -1.f);
    k_gemm<128><<<1563, 256, 0, stream>>>(X0, Tx1, Tx2, wpad + OCH0, h0, d_out, 0, flag);
    // layer 1 (F=64)
    k_prop<64><<<12500, 256, 0, stream>>>(h0, csr_col, csr_norm, offs, Tx1, nullptr, 1.f, 0.f);
    k_prop<64><<<12500, 256, 0, stream>>>(Tx1, csr_col, csr_norm, offs, Tx2, h0, 2.f, -1.f);
    k_gemm<64><<<1563, 256, 0, stream>>>(h0, Tx1, Tx2, wpad + OCH1, h1, d_out, 64, flag);
    // layer 2
    k_prop<64><<<12500, 256, 0, stream>>>(h1, csr_col, csr_norm, offs, Tx1, nullptr, 1.f, 0.f);
    k_prop<64><<<12500, 256, 0, stream>>>(Tx1, csr_col, csr_norm, offs, Tx2, h1, 2.f, -1.f);
    k_gemm<64><<<1563, 256, 0, stream>>>(h1, Tx1, Tx2, wpad + OCH2, h2, d_out, 128, flag);
    // layer 3
    k_prop<64><<<12500, 256, 0, stream>>>(h2, csr_col, csr_norm, offs, Tx1, nullptr, 1.f, 0.f);
    k_prop<64><<<12500, 256, 0, stream>>>(Tx1, csr_col, csr_norm, offs, Tx2, h2, 2.f, -1.f);
    k_gemm<64><<<1563, 256, 0, stream>>>(h2, Tx1, Tx2, wpad + OCH3, h3, d_out, 192, flag);

    // classifier
    k_cls1<<<dim3(1563, 4), 256, 0, stream>>>(h0, h1, h2, h3, wpad, z);
    k_cls2<<<12500, 256, 0, stream>>>(z, wpad, flag, d_out);
    (void)in_sizes; (void)n_in; (void)out_size; (void)ws_size;
}

// Round 4
// 1935.019 us; speedup vs baseline: 1.6770x; 1.6770x over previous
//
#include <hip/hip_runtime.h>

#define NN 50000
#define EE 1600000

using u16 = unsigned short;
using u32 = unsigned int;

typedef float f32x4 __attribute__((ext_vector_type(4)));
typedef __bf16 bf16x8 __attribute__((ext_vector_type(8)));
typedef unsigned short u16x8 __attribute__((ext_vector_type(8)));

struct alignas(8) U16x4 { u16 a, b, c, d; };
struct PtrTab { const void* p[20]; };

// canonical fp32 weight-pad offsets
#define OW1 0
#define OB1 768
#define OG 896
#define OBB 1024
#define ORM 1152
#define ORV 1280
#define OW2 1408
#define OB2 17792
#define OCH0 17920
#define OCH1 42496
#define OCH2 54784
#define OCH3 67072
#define OCW1 79360
#define OCB1 144896
#define OCG 145152
#define OCBB 145408
#define OCRM 145664
#define OCRV 145920
#define OCW2 146176
#define OCB2 146688
#define OTOT 146690

// element offsets within d_out (dtype-independent in elements)
#define LG_OFF ((size_t)NN * 256)
#define EW_OFF ((size_t)NN * 256 + (size_t)NN * 2)

__device__ __forceinline__ float bf2f(u16 u) { return __builtin_bit_cast(float, (u32)u << 16); }
__device__ __forceinline__ float bfl(u32 u) { return __builtin_bit_cast(float, u << 16); }
__device__ __forceinline__ float bfh(u32 u) { return __builtin_bit_cast(float, u & 0xffff0000u); }
__device__ __forceinline__ u16 f2bf(float f) {
    u32 u = __builtin_bit_cast(u32, f);
    return (u16)((u + 0x7fffu + ((u >> 16) & 1u)) >> 16);
}

// Input dtype detector: flag=1 -> bf16 inputs, 0 -> fp32 inputs.
__global__ __launch_bounds__(256) void k_detect(const u16* __restrict__ f, int* __restrict__ flag) {
    __shared__ int bad;
    if (threadIdx.x == 0) bad = 0;
    __syncthreads();
    u16 u = f[threadIdx.x];
    int e = (u >> 7) & 0xFF;
    if (e >= 0x90) atomicAdd(&bad, 1);
    __syncthreads();
    if (threadIdx.x == 0) flag[0] = (bad < 16) ? 1 : 0;
}

// Convert all 20 weight arrays into canonical fp32 pad.
__global__ __launch_bounds__(256) void k_wconv(PtrTab tab, const int* __restrict__ flag,
                                               float* __restrict__ wpad) {
    const int SZ[20] = {768, 128, 128, 128, 128, 128, 16384, 128, 24576, 12288, 12288, 12288,
                        65536, 256, 256, 256, 256, 256, 512, 2};
    const int OF[20] = {OW1, OB1, OG, OBB, ORM, ORV, OW2, OB2, OCH0, OCH1, OCH2, OCH3,
                        OCW1, OCB1, OCG, OCBB, OCRM, OCRV, OCW2, OCB2};
    int a = blockIdx.x;
    int n = SZ[a];
    float* dst = wpad + OF[a];
    if (flag[0] != 0) {
        const u16* s = (const u16*)tab.p[a];
        for (int i = threadIdx.x; i < n; i += 256) dst[i] = bf2f(s[i]);
    } else {
        const float* s = (const float*)tab.p[a];
        for (int i = threadIdx.x; i < n; i += 256) dst[i] = s[i];
    }
}

// Fold PAE BN into W2 (MFMA B-frag swizzled bf16) + b2'.
__global__ __launch_bounds__(128) void k_fold(const float* __restrict__ wpad,
                                              u16* __restrict__ W2s, float* __restrict__ b2p) {
    const float* g = wpad + OG;
    const float* b = wpad + OBB;
    const float* rm = wpad + ORM;
    const float* rv = wpad + ORV;
    const float* w2 = wpad + OW2;
    const float* b2 = wpad + OB2;
    int blk = blockIdx.x, tid = threadIdx.x;
    if (blk < 32) {
        int kc = blk >> 3, jt = blk & 7;
        int lane = tid & 63, jh = tid >> 6;
        for (int jj = 0; jj < 4; jj++) {
            int j = jh * 4 + jj;
            int k = kc * 32 + (lane >> 4) * 8 + j;
            int jcol = jt * 16 + (lane & 15);
            float s = g[k] * rsqrtf(rv[k] + 1e-5f);
            W2s[((kc * 8 + jt) * 64 + lane) * 8 + j] = f2bf(s * w2[k * 128 + jcol]);
        }
    } else {
        if (tid < 128) {
            int j = tid;
            float acc = b2[j];
            for (int k = 0; k < 128; k++) {
                float s = g[k] * rsqrtf(rv[k] + 1e-5f);
                float t = b[k] - rm[k] * s;
                acc += t * w2[k * 128 + j];
            }
            b2p[j] = acc;
        }
    }
}

// features (either dtype) -> bf16 X0.
__global__ __launch_bounds__(256) void k_x0(const void* __restrict__ feat, const int* __restrict__ flag,
                                            u16* __restrict__ X0) {
    int i = blockIdx.x * 256 + threadIdx.x;
    if (flag[0] != 0) {
        ((uint4*)X0)[i] = ((const uint4*)feat)[i];
    } else {
        const float4* f = (const float4*)feat;
        float4 a = f[2 * i], b = f[2 * i + 1];
        u16x8 o;
        o[0] = f2bf(a.x); o[1] = f2bf(a.y); o[2] = f2bf(a.z); o[3] = f2bf(a.w);
        o[4] = f2bf(b.x); o[5] = f2bf(b.y); o[6] = f2bf(b.z); o[7] = f2bf(b.w);
        ((uint4*)X0)[i] = __builtin_bit_cast(uint4, o);
    }
}

// PAE: A = relu(Z@W1+b1) on VALU (fragments staged once), H = A@W2' via MFMA
// with jt-outer loop (2 live accumulators), cosine -> edge weight.
// NO min-waves hint: live set ~100 VGPRs; a (256,4) hint forced 64 VGPRs and
// spilled the staged fragments to scratch (4 GB HBM re-read, round 3).
__global__ __launch_bounds__(256) void k_pae(const void* __restrict__ zin, const float* __restrict__ wpad,
                                             const u16* __restrict__ W2sg, const float* __restrict__ b2p,
                                             const int* __restrict__ ei, const int* __restrict__ flag,
                                             float* __restrict__ ewf, void* __restrict__ dout,
                                             float* __restrict__ deg, int* __restrict__ cnt) {
    __shared__ __align__(16) u16 sW2[16384];
    __shared__ float sW1[6 * 128];
    __shared__ float sB1[128];
    __shared__ float sB2[128];
    int tid = threadIdx.x;
    for (int i = tid; i < 8192; i += 256) ((u32*)sW2)[i] = ((const u32*)W2sg)[i];
    for (int i = tid; i < 768; i += 256) sW1[i] = wpad[OW1 + i];
    if (tid < 128) { sB1[tid] = wpad[OB1 + tid]; sB2[tid] = b2p[tid]; }
    __syncthreads();

    bool isbf = flag[0] != 0;
    int wv = __builtin_amdgcn_readfirstlane(tid >> 6);
    int lane = tid & 63;
    int quad = lane >> 4, lrow = lane & 15, jc = lane & 15;
    int gw = blockIdx.x * 4 + wv;
    const int ngroups = EE / 16;

    for (int gidx = gw; gidx < ngroups; gidx += gridDim.x * 4) {
        int e0 = gidx * 16;
        float z1[6], z2[6];
        if (isbf) {
            const u32* zp = (const u32*)((const u16*)zin + (size_t)(e0 + lrow) * 12);
            u32 u0 = zp[0], u1 = zp[1], u2 = zp[2], u3 = zp[3], u4 = zp[4], u5 = zp[5];
            z1[0] = bfl(u0); z1[1] = bfh(u0); z1[2] = bfl(u1); z1[3] = bfh(u1); z1[4] = bfl(u2); z1[5] = bfh(u2);
            z2[0] = bfl(u3); z2[1] = bfh(u3); z2[2] = bfl(u4); z2[3] = bfh(u4); z2[4] = bfl(u5); z2[5] = bfh(u5);
        } else {
            const float4* zp = (const float4*)((const float*)zin + (size_t)(e0 + lrow) * 12);
            float4 p0 = zp[0], p1 = zp[1], p2 = zp[2];
            z1[0] = p0.x; z1[1] = p0.y; z1[2] = p0.z; z1[3] = p0.w; z1[4] = p1.x; z1[5] = p1.y;
            z2[0] = p1.z; z2[1] = p1.w; z2[2] = p2.x; z2[3] = p2.y; z2[4] = p2.z; z2[5] = p2.w;
        }

        // Stage A fragments for all 4 kc chunks (32 VGPRs total)
        bf16x8 a1f[4], a2f[4];
#pragma unroll
        for (int kc = 0; kc < 4; kc++) {
            u16x8 a1u, a2u;
            int kbase = kc * 32 + quad * 8;
#pragma unroll
            for (int j = 0; j < 8; j++) {
                int k = kbase + j;
                float s1 = sB1[k], s2 = s1;
#pragma unroll
                for (int m = 0; m < 6; m++) {
                    float wm = sW1[m * 128 + k];
                    s1 = fmaf(z1[m], wm, s1);
                    s2 = fmaf(z2[m], wm, s2);
                }
                a1u[j] = f2bf(fmaxf(s1, 0.f));
                a2u[j] = f2bf(fmaxf(s2, 0.f));
            }
            a1f[kc] = __builtin_bit_cast(bf16x8, a1u);
            a2f[kc] = __builtin_bit_cast(bf16x8, a2u);
        }

        float num[4] = {0, 0, 0, 0}, q1[4] = {0, 0, 0, 0}, q2[4] = {0, 0, 0, 0};
        // jt-outer: only 2 f32x4 accumulators live at a time
#pragma unroll
        for (int jt = 0; jt < 8; jt++) {
            f32x4 acc1 = {0.f, 0.f, 0.f, 0.f}, acc2 = {0.f, 0.f, 0.f, 0.f};
#pragma unroll
            for (int kc = 0; kc < 4; kc++) {
                bf16x8 bb = *reinterpret_cast<const bf16x8*>(&sW2[((kc * 8 + jt) * 64 + lane) * 8]);
                acc1 = __builtin_amdgcn_mfma_f32_16x16x32_bf16(a1f[kc], bb, acc1, 0, 0, 0);
                acc2 = __builtin_amdgcn_mfma_f32_16x16x32_bf16(a2f[kc], bb, acc2, 0, 0, 0);
            }
            float bbias = sB2[jt * 16 + jc];
#pragma unroll
            for (int r = 0; r < 4; r++) {
                float h1 = acc1[r] + bbias;
                float h2 = acc2[r] + bbias;
                num[r] = fmaf(h1, h2, num[r]);
                q1[r] = fmaf(h1, h1, q1[r]);
                q2[r] = fmaf(h2, h2, q2[r]);
            }
        }
#pragma unroll
        for (int off = 1; off < 16; off <<= 1) {
#pragma unroll
            for (int r = 0; r < 4; r++) {
                num[r] += __shfl_xor(num[r], off);
                q1[r] += __shfl_xor(q1[r], off);
                q2[r] += __shfl_xor(q2[r], off);
            }
        }
        if (jc == 0) {
#pragma unroll
            for (int r = 0; r < 4; r++) {
                int e = e0 + quad * 4 + r;
                float den = fmaxf(sqrtf(q1[r]) * sqrtf(q2[r]), 1e-8f);
                float wgt = (num[r] / den + 1.f) * 0.5f;
                if (!(wgt == wgt)) wgt = 0.5f;  // NaN guard: makes failures localizable
                ewf[e] = wgt;
                if (isbf) ((u16*)dout)[EW_OFF + e] = f2bf(wgt);
                else ((float*)dout)[EW_OFF + e] = wgt;
                int row = ei[e];
                atomicAdd(deg + row, wgt);
                atomicAdd(cnt + row, 1);
            }
        }
    }
}

// Exclusive scan of cnt -> offs; fused dis = rsqrt(deg).
__global__ __launch_bounds__(1024) void k_scan(const int* __restrict__ cnt, const float* __restrict__ deg,
                                               int* __restrict__ offs, float* __restrict__ dis) {
    __shared__ int wsum[16];
    __shared__ int carry;
    int tid = threadIdx.x;
    int wv = tid >> 6, lane = tid & 63;
    if (tid == 0) carry = 0;
    __syncthreads();
    for (int c = 0; c < 49; c++) {
        int i = c * 1024 + tid;
        int v = (i < NN) ? cnt[i] : 0;
        if (i < NN) {
            float d = deg[i];
            dis[i] = d > 0.f ? rsqrtf(d) : 0.f;
        }
        int x = v;
#pragma unroll
        for (int off = 1; off < 64; off <<= 1) {
            int t = __shfl_up(x, off);
            if (lane >= off) x += t;
        }
        if (lane == 63) wsum[wv] = x;
        __syncthreads();
        if (tid < 16) {
            int s = wsum[tid];
#pragma unroll
            for (int off = 1; off < 16; off <<= 1) {
                int t = __shfl_up(s, off, 16);
                if (tid >= off) s += t;
            }
            wsum[tid] = s;
        }
        __syncthreads();
        int base = carry + (wv > 0 ? wsum[wv - 1] : 0);
        if (i < NN) offs[i] = base + x - v;
        __syncthreads();
        if (tid == 0) carry += wsum[15];
        __syncthreads();
    }
    if (tid == 0) offs[NN] = carry;
}

// CSR scatter: fused (col, norm) uint2 metadata — one 8B load per edge in prop.
__global__ __launch_bounds__(256) void k_csr(const int* __restrict__ ei, const float* __restrict__ ewf,
                                             const float* __restrict__ dis, const int* __restrict__ offs,
                                             int* __restrict__ cursor, uint2* __restrict__ csr_meta) {
    int e = blockIdx.x * 256 + threadIdx.x;
    int r = ei[e], c = ei[EE + e];
    float wgt = ewf[e];
    int pos = offs[r] + atomicAdd(cursor + r, 1);
    float nrm = -dis[r] * wgt * dis[c];
    csr_meta[pos] = make_uint2((u32)c, __builtin_bit_cast(u32, nrm));
}

// Propagation over bf16 node features, fp32 accumulate. One wave per node,
// 16 lanes per edge; 8 edges in flight (2x unrolled) for MLP.
template <int F>
__global__ __launch_bounds__(256) void k_prop(const u16* __restrict__ src, const uint2* __restrict__ csr_meta,
                                              const int* __restrict__ offs,
                                              u16* __restrict__ out, const u16* __restrict__ base,
                                              float alpha, float beta) {
    int lane = threadIdx.x & 63;
    int wv = threadIdx.x >> 6;
    int node = blockIdx.x * 4 + wv;
    int s = offs[node], e = offs[node + 1];
    int sub = lane >> 4;   // which of 4 edges this lane group handles
    int fl = lane & 15;    // position within the feature row

    if (F == 128) {
        const uint4* sv = (const uint4*)src;  // row = 16 uint4 (128 bf16)
        float a[8] = {0, 0, 0, 0, 0, 0, 0, 0};
        int p = s;
        for (; p + 7 < e; p += 8) {
            uint2 m0 = csr_meta[p + sub];
            uint2 m1 = csr_meta[p + 4 + sub];
            uint4 v0 = sv[(size_t)m0.x * 16 + fl];
            uint4 v1 = sv[(size_t)m1.x * 16 + fl];
            float w0 = __builtin_bit_cast(float, m0.y);
            float w1 = __builtin_bit_cast(float, m1.y);
            a[0] = fmaf(w0, bfl(v0.x), a[0]); a[1] = fmaf(w0, bfh(v0.x), a[1]);
            a[2] = fmaf(w0, bfl(v0.y), a[2]); a[3] = fmaf(w0, bfh(v0.y), a[3]);
            a[4] = fmaf(w0, bfl(v0.z), a[4]); a[5] = fmaf(w0, bfh(v0.z), a[5]);
            a[6] = fmaf(w0, bfl(v0.w), a[6]); a[7] = fmaf(w0, bfh(v0.w), a[7]);
            a[0] = fmaf(w1, bfl(v1.x), a[0]); a[1] = fmaf(w1, bfh(v1.x), a[1]);
            a[2] = fmaf(w1, bfl(v1.y), a[2]); a[3] = fmaf(w1, bfh(v1.y), a[3]);
            a[4] = fmaf(w1, bfl(v1.z), a[4]); a[5] = fmaf(w1, bfh(v1.z), a[5]);
            a[6] = fmaf(w1, bfl(v1.w), a[6]); a[7] = fmaf(w1, bfh(v1.w), a[7]);
        }
        if (p + 3 < e) {
            uint2 m0 = csr_meta[p + sub];
            uint4 v0 = sv[(size_t)m0.x * 16 + fl];
            float w0 = __builtin_bit_cast(float, m0.y);
            a[0] = fmaf(w0, bfl(v0.x), a[0]); a[1] = fmaf(w0, bfh(v0.x), a[1]);
            a[2] = fmaf(w0, bfl(v0.y), a[2]); a[3] = fmaf(w0, bfh(v0.y), a[3]);
            a[4] = fmaf(w0, bfl(v0.z), a[4]); a[5] = fmaf(w0, bfh(v0.z), a[5]);
            a[6] = fmaf(w0, bfl(v0.w), a[6]); a[7] = fmaf(w0, bfh(v0.w), a[7]);
            p += 4;
        }
#pragma unroll
        for (int i = 0; i < 8; i++) {
            a[i] += __shfl_xor(a[i], 16);
            a[i] += __shfl_xor(a[i], 32);
        }
        if (sub == 0) {
            for (; p < e; p++) {
                uint2 m0 = csr_meta[p];
                uint4 v = sv[(size_t)m0.x * 16 + fl];
                float w = __builtin_bit_cast(float, m0.y);
                a[0] = fmaf(w, bfl(v.x), a[0]); a[1] = fmaf(w, bfh(v.x), a[1]);
                a[2] = fmaf(w, bfl(v.y), a[2]); a[3] = fmaf(w, bfh(v.y), a[3]);
                a[4] = fmaf(w, bfl(v.z), a[4]); a[5] = fmaf(w, bfh(v.z), a[5]);
                a[6] = fmaf(w, bfl(v.w), a[6]); a[7] = fmaf(w, bfh(v.w), a[7]);
            }
            float o[8];
#pragma unroll
            for (int i = 0; i < 8; i++) o[i] = alpha * a[i];
            if (beta != 0.f) {
                uint4 bv = ((const uint4*)base)[(size_t)node * 16 + fl];
                o[0] = fmaf(beta, bfl(bv.x), o[0]); o[1] = fmaf(beta, bfh(bv.x), o[1]);
                o[2] = fmaf(beta, bfl(bv.y), o[2]); o[3] = fmaf(beta, bfh(bv.y), o[3]);
                o[4] = fmaf(beta, bfl(bv.z), o[4]); o[5] = fmaf(beta, bfh(bv.z), o[5]);
                o[6] = fmaf(beta, bfl(bv.w), o[6]); o[7] = fmaf(beta, bfh(bv.w), o[7]);
            }
            uint4 ov;
            ov.x = (u32)f2bf(o[0]) | ((u32)f2bf(o[1]) << 16);
            ov.y = (u32)f2bf(o[2]) | ((u32)f2bf(o[3]) << 16);
            ov.z = (u32)f2bf(o[4]) | ((u32)f2bf(o[5]) << 16);
            ov.w = (u32)f2bf(o[6]) | ((u32)f2bf(o[7]) << 16);
            ((uint4*)out)[(size_t)node * 16 + fl] = ov;
        }
    } else {
        const uint2* sv = (const uint2*)src;  // row = 16 uint2 (64 bf16)
        float a[4] = {0, 0, 0, 0};
        int p = s;
        for (; p + 7 < e; p += 8) {
            uint2 m0 = csr_meta[p + sub];
            uint2 m1 = csr_meta[p + 4 + sub];
            uint2 v0 = sv[(size_t)m0.x * 16 + fl];
            uint2 v1 = sv[(size_t)m1.x * 16 + fl];
            float w0 = __builtin_bit_cast(float, m0.y);
            float w1 = __builtin_bit_cast(float, m1.y);
            a[0] = fmaf(w0, bfl(v0.x), a[0]); a[1] = fmaf(w0, bfh(v0.x), a[1]);
            a[2] = fmaf(w0, bfl(v0.y), a[2]); a[3] = fmaf(w0, bfh(v0.y), a[3]);
            a[0] = fmaf(w1, bfl(v1.x), a[0]); a[1] = fmaf(w1, bfh(v1.x), a[1]);
            a[2] = fmaf(w1, bfl(v1.y), a[2]); a[3] = fmaf(w1, bfh(v1.y), a[3]);
        }
        if (p + 3 < e) {
            uint2 m0 = csr_meta[p + sub];
            uint2 v0 = sv[(size_t)m0.x * 16 + fl];
            float w0 = __builtin_bit_cast(float, m0.y);
            a[0] = fmaf(w0, bfl(v0.x), a[0]); a[1] = fmaf(w0, bfh(v0.x), a[1]);
            a[2] = fmaf(w0, bfl(v0.y), a[2]); a[3] = fmaf(w0, bfh(v0.y), a[3]);
            p += 4;
        }
#pragma unroll
        for (int i = 0; i < 4; i++) {
            a[i] += __shfl_xor(a[i], 16);
            a[i] += __shfl_xor(a[i], 32);
        }
        if (sub == 0) {
            for (; p < e; p++) {
                uint2 m0 = csr_meta[p];
                uint2 v = sv[(size_t)m0.x * 16 + fl];
                float w = __builtin_bit_cast(float, m0.y);
                a[0] = fmaf(w, bfl(v.x), a[0]); a[1] = fmaf(w, bfh(v.x), a[1]);
                a[2] = fmaf(w, bfl(v.y), a[2]); a[3] = fmaf(w, bfh(v.y), a[3]);
            }
            float o[4];
#pragma unroll
            for (int i = 0; i < 4; i++) o[i] = alpha * a[i];
            if (beta != 0.f) {
                uint2 bv = ((const uint2*)base)[(size_t)node * 16 + fl];
                o[0] = fmaf(beta, bfl(bv.x), o[0]); o[1] = fmaf(beta, bfh(bv.x), o[1]);
                o[2] = fmaf(beta, bfl(bv.y), o[2]); o[3] = fmaf(beta, bfh(bv.y), o[3]);
            }
            uint2 ov;
            ov.x = (u32)f2bf(o[0]) | ((u32)f2bf(o[1]) << 16);
            ov.y = (u32)f2bf(o[2]) | ((u32)f2bf(o[3]) << 16);
            ((uint2*)out)[(size_t)node * 16 + fl] = ov;
        }
    }
}

// ChebConv mix -> bf16 h + jk slice (out dtype).
template <int F>
__global__ __launch_bounds__(256) void k_gemm(const u16* __restrict__ X0, const u16* __restrict__ X1,
                                              const u16* __restrict__ X2, const float* __restrict__ Wg,
                                              u16* __restrict__ Hout, void* __restrict__ jk, int jkoff,
                                              const int* __restrict__ flag) {
    __shared__ u16 sW[3 * 64 * (F + 4)];
    int tid = threadIdx.x;
    for (int idx = tid; idx < 3 * F * 64; idx += 256) {
        int j = idx & 63;
        int rest = idx >> 6;
        int k = rest % F;
        int p = rest / F;
        sW[(p * 64 + j) * (F + 4) + k] = f2bf(Wg[(p * F + k) * 64 + j]);
    }
    __syncthreads();
    bool isbf = flag[0] != 0;
    int wv = __builtin_amdgcn_readfirstlane(tid >> 6);
    int lane = tid & 63;
    int nbase = blockIdx.x * 32 + wv * 8;
    float acc[8] = {0, 0, 0, 0, 0, 0, 0, 0};
    const u16* Xs[3] = {X0, X1, X2};
    for (int p = 0; p < 3; p++) {
        const u16* Xp = Xs[p];
        const u16* wrow = &sW[(p * 64 + lane) * (F + 4)];
        const u16* rp[8];
#pragma unroll
        for (int i = 0; i < 8; i++) {
            int n = nbase + i;
            if (n > NN - 1) n = NN - 1;
            rp[i] = Xp + (size_t)n * F;
        }
        for (int k = 0; k < F; k += 4) {
            U16x4 w4 = *(const U16x4*)&wrow[k];
            float w0 = bf2f(w4.a), w1 = bf2f(w4.b), w2 = bf2f(w4.c), w3 = bf2f(w4.d);
#pragma unroll
            for (int i = 0; i < 8; i++) {
                U16x4 xv = *(const U16x4*)(rp[i] + k);
                acc[i] = fmaf(bf2f(xv.a), w0, acc[i]);
                acc[i] = fmaf(bf2f(xv.b), w1, acc[i]);
                acc[i] = fmaf(bf2f(xv.c), w2, acc[i]);
                acc[i] = fmaf(bf2f(xv.d), w3, acc[i]);
            }
        }
    }
#pragma unroll
    for (int i = 0; i < 8; i++) {
        int n = nbase + i;
        if (n < NN) {
            float v = fmaxf(acc[i], 0.f);
            Hout[(size_t)n * 64 + lane] = f2bf(v);
            if (isbf) ((u16*)jk)[(size_t)n * 256 + jkoff + lane] = f2bf(v);
            else ((float*)jk)[(size_t)n * 256 + jkoff + lane] = v;
        }
    }
}

// Classifier stage 1 -> internal bf16 z.
__global__ __launch_bounds__(256) void k_cls1(const u16* __restrict__ h0, const u16* __restrict__ h1,
                                              const u16* __restrict__ h2, const u16* __restrict__ h3,
                                              const float* __restrict__ wpad, u16* __restrict__ zout) {
    __shared__ u16 sW[64 * 260];
    int tid = threadIdx.x;
    int jch = blockIdx.y;
    const float* w1 = wpad + OCW1;
    for (int idx = tid; idx < 64 * 256; idx += 256) {
        int j = idx & 63, k = idx >> 6;
        sW[j * 260 + k] = f2bf(w1[k * 256 + jch * 64 + j]);
    }
    __syncthreads();
    int wv = __builtin_amdgcn_readfirstlane(tid >> 6);
    int lane = tid & 63;
    int nbase = blockIdx.x * 32 + wv * 8;
    float acc[8] = {0, 0, 0, 0, 0, 0, 0, 0};
    const u16* hs[4] = {h0, h1, h2, h3};
    const u16* wrow = &sW[lane * 260];
    for (int l = 0; l < 4; l++) {
        const u16* hb = hs[l];
        const u16* rp[8];
#pragma unroll
        for (int i = 0; i < 8; i++) {
            int n = nbase + i;
            if (n > NN - 1) n = NN - 1;
            rp[i] = hb + (size_t)n * 64;
        }
        for (int kk = 0; kk < 64; kk += 4) {
            U16x4 w4 = *(const U16x4*)&wrow[l * 64 + kk];
            float w0 = bf2f(w4.a), w1f = bf2f(w4.b), w2f = bf2f(w4.c), w3f = bf2f(w4.d);
#pragma unroll
            for (int i = 0; i < 8; i++) {
                U16x4 xv = *(const U16x4*)(rp[i] + kk);
                acc[i] = fmaf(bf2f(xv.a), w0, acc[i]);
                acc[i] = fmaf(bf2f(xv.b), w1f, acc[i]);
                acc[i] = fmaf(bf2f(xv.c), w2f, acc[i]);
                acc[i] = fmaf(bf2f(xv.d), w3f, acc[i]);
            }
        }
    }
    int j = jch * 64 + lane;
    float bb1 = wpad[OCB1 + j];
    float s = wpad[OCG + j] * rsqrtf(wpad[OCRV + j] + 1e-5f);
    float t = wpad[OCBB + j] - wpad[OCRM + j] * s;
#pragma unroll
    for (int i = 0; i < 8; i++) {
        int n = nbase + i;
        if (n < NN) {
            float v = fmaxf(acc[i] + bb1, 0.f) * s + t;
            zout[(size_t)n * 256 + j] = f2bf(v);
        }
    }
}

// Classifier stage 2: logit into d_out at LG_OFF (out dtype).
__global__ __launch_bounds__(256) void k_cls2(const u16* __restrict__ z, const float* __restrict__ wpad,
                                              const int* __restrict__ flag, void* __restrict__ dout) {
    __shared__ float sw2[512];
    __shared__ float sb2[2];
    int tid = threadIdx.x;
    for (int i = tid; i < 512; i += 256) sw2[i] = wpad[OCW2 + i];
    if (tid < 2) sb2[tid] = wpad[OCB2 + tid];
    __syncthreads();
    bool isbf = flag[0] != 0;
    int wv = __builtin_amdgcn_readfirstlane(tid >> 6);
    int lane = tid & 63;
    int node = blockIdx.x * 4 + wv;
    U16x4 zv = *(const U16x4*)(z + (size_t)node * 256 + lane * 4);
    float zf[4] = {bf2f(zv.a), bf2f(zv.b), bf2f(zv.c), bf2f(zv.d)};
    float p0 = 0.f, p1 = 0.f;
#pragma unroll
    for (int m = 0; m < 4; m++) {
        int k = lane * 4 + m;
        p0 = fmaf(zf[m], sw2[k * 2 + 0], p0);
        p1 = fmaf(zf[m], sw2[k * 2 + 1], p1);
    }
#pragma unroll
    for (int off = 1; off < 64; off <<= 1) {
        p0 += __shfl_xor(p0, off);
        p1 += __shfl_xor(p1, off);
    }
    if (lane == 0) {
        float l0 = p0 + sb2[0], l1 = p1 + sb2[1];
        if (isbf) {
            u32 pack = (u32)f2bf(l0) | ((u32)f2bf(l1) << 16);
            *(u32*)((u16*)dout + LG_OFF + (size_t)node * 2) = pack;
        } else {
            float2 o = {l0, l1};
            *(float2*)((float*)dout + LG_OFF + (size_t)node * 2) = o;
        }
    }
}

extern "C" void kernel_launch(void* const* d_in, const int* in_sizes, int n_in,
                              void* d_out, int out_size, void* d_ws, size_t ws_size,
                              hipStream_t stream) {
    const void* features = d_in[0];
    const int* ei = (const int*)d_in[1];
    const void* zin = d_in[2];

    char* w = (char*)d_ws;
    auto alloc = [&](size_t bytes) -> void* {
        void* p = (void*)w;
        w += (bytes + 255) & ~(size_t)255;
        return p;
    };
    u16* X0 = (u16*)alloc((size_t)NN * 128 * 2);
    u16* Tx1 = (u16*)alloc((size_t)NN * 128 * 2);
    u16* Tx2 = (u16*)alloc((size_t)NN * 128 * 2);
    u16* h0 = (u16*)alloc((size_t)NN * 64 * 2);
    u16* h1 = (u16*)alloc((size_t)NN * 64 * 2);
    u16* h2 = (u16*)alloc((size_t)NN * 64 * 2);
    u16* h3 = (u16*)alloc((size_t)NN * 64 * 2);
    float* ewf = (float*)alloc((size_t)EE * 4);
    uint2* csr_meta = (uint2*)alloc((size_t)EE * 8);
    float* deg = (float*)alloc((size_t)NN * 4);
    int* cnt = (int*)alloc((size_t)NN * 4);
    int* cursor = (int*)alloc((size_t)NN * 4);
    float* dis = (float*)alloc((size_t)NN * 4);
    int* offs = (int*)alloc((size_t)(NN + 1) * 4);
    u16* W2s = (u16*)alloc((size_t)16384 * 2);
    float* b2p = (float*)alloc((size_t)128 * 4);
    float* wpad = (float*)alloc((size_t)OTOT * 4);
    int* flag = (int*)alloc(256);
    u16* z = X0;  // reuses X0+Tx1 region (25.6MB), free after layer-3 gemm

    hipMemsetAsync(deg, 0, (size_t)((char*)dis - (char*)deg), stream);

    PtrTab tab;
    for (int i = 0; i < 20; i++) tab.p[i] = d_in[3 + i];

    k_detect<<<1, 256, 0, stream>>>((const u16*)features, flag);
    k_wconv<<<20, 256, 0, stream>>>(tab, flag, wpad);
    k_fold<<<33, 128, 0, stream>>>(wpad, W2s, b2p);
    k_x0<<<3125, 256, 0, stream>>>(features, flag, X0);
    k_pae<<<1024, 256, 0, stream>>>(zin, wpad, W2s, b2p, ei, flag, ewf, d_out, deg, cnt);
    k_scan<<<1, 1024, 0, stream>>>(cnt, deg, offs, dis);
    k_csr<<<EE / 256, 256, 0, stream>>>(ei, ewf, dis, offs, cursor, csr_meta);

    // layer 0 (F=128)
    k_prop<128><<<12500, 256, 0, stream>>>(X0, csr_meta, offs, Tx1, nullptr, 1.f, 0.f);
    k_prop<128><<<12500, 256, 0, stream>>>(Tx1, csr_meta, offs, Tx2, X0, 2.f, -1.f);
    k_gemm<128><<<1563, 256, 0, stream>>>(X0, Tx1, Tx2, wpad + OCH0, h0, d_out, 0, flag);
    // layer 1 (F=64)
    k_prop<64><<<12500, 256, 0, stream>>>(h0, csr_meta, offs, Tx1, nullptr, 1.f, 0.f);
    k_prop<64><<<12500, 256, 0, stream>>>(Tx1, csr_meta, offs, Tx2, h0, 2.f, -1.f);
    k_gemm<64><<<1563, 256, 0, stream>>>(h0, Tx1, Tx2, wpad + OCH1, h1, d_out, 64, flag);
    // layer 2
    k_prop<64><<<12500, 256, 0, stream>>>(h1, csr_meta, offs, Tx1, nullptr, 1.f, 0.f);
    k_prop<64><<<12500, 256, 0, stream>>>(Tx1, csr_meta, offs, Tx2, h1, 2.f, -1.f);
    k_gemm<64><<<1563, 256, 0, stream>>>(h1, Tx1, Tx2, wpad + OCH2, h2, d_out, 128, flag);
    // layer 3
    k_prop<64><<<12500, 256, 0, stream>>>(h2, csr_meta, offs, Tx1, nullptr, 1.f, 0.f);
    k_prop<64><<<12500, 256, 0, stream>>>(Tx1, csr_meta, offs, Tx2, h2, 2.f, -1.f);
    k_gemm<64><<<1563, 256, 0, stream>>>(h2, Tx1, Tx2, wpad + OCH3, h3, d_out, 192, flag);

    // classifier
    k_cls1<<<dim3(1563, 4), 256, 0, stream>>>(h0, h1, h2, h3, wpad, z);
    k_cls2<<<12500, 256, 0, stream>>>(z, wpad, flag, d_out);
    (void)in_sizes; (void)n_in; (void)out_size; (void)ws_size;
}

// Round 5
// 1928.927 us; speedup vs baseline: 1.6823x; 1.0032x over previous
//
#include <hip/hip_runtime.h>

#define NN 50000
#define EE 1600000

using u16 = unsigned short;
using u32 = unsigned int;

typedef float f32x4 __attribute__((ext_vector_type(4)));
typedef __bf16 bf16x8 __attribute__((ext_vector_type(8)));
typedef unsigned short u16x8 __attribute__((ext_vector_type(8)));

struct alignas(8) U16x4 { u16 a, b, c, d; };
struct PtrTab { const void* p[20]; };

// canonical fp32 weight-pad offsets
#define OW1 0
#define OB1 768
#define OG 896
#define OBB 1024
#define ORM 1152
#define ORV 1280
#define OW2 1408
#define OB2 17792
#define OCH0 17920
#define OCH1 42496
#define OCH2 54784
#define OCH3 67072
#define OCW1 79360
#define OCB1 144896
#define OCG 145152
#define OCBB 145408
#define OCRM 145664
#define OCRV 145920
#define OCW2 146176
#define OCB2 146688
#define OTOT 146690

// element offsets within d_out (dtype-independent in elements)
#define LG_OFF ((size_t)NN * 256)
#define EW_OFF ((size_t)NN * 256 + (size_t)NN * 2)

__device__ __forceinline__ float bf2f(u16 u) { return __builtin_bit_cast(float, (u32)u << 16); }
__device__ __forceinline__ float bfl(u32 u) { return __builtin_bit_cast(float, u << 16); }
__device__ __forceinline__ float bfh(u32 u) { return __builtin_bit_cast(float, u & 0xffff0000u); }
__device__ __forceinline__ u16 f2bf(float f) {
    u32 u = __builtin_bit_cast(u32, f);
    return (u16)((u + 0x7fffu + ((u >> 16) & 1u)) >> 16);
}

// Input dtype detector: flag=1 -> bf16 inputs, 0 -> fp32 inputs.
__global__ __launch_bounds__(256) void k_detect(const u16* __restrict__ f, int* __restrict__ flag) {
    __shared__ int bad;
    if (threadIdx.x == 0) bad = 0;
    __syncthreads();
    u16 u = f[threadIdx.x];
    int e = (u >> 7) & 0xFF;
    if (e >= 0x90) atomicAdd(&bad, 1);
    __syncthreads();
    if (threadIdx.x == 0) flag[0] = (bad < 16) ? 1 : 0;
}

// Convert all 20 weight arrays into canonical fp32 pad.
__global__ __launch_bounds__(256) void k_wconv(PtrTab tab, const int* __restrict__ flag,
                                               float* __restrict__ wpad) {
    const int SZ[20] = {768, 128, 128, 128, 128, 128, 16384, 128, 24576, 12288, 12288, 12288,
                        65536, 256, 256, 256, 256, 256, 512, 2};
    const int OF[20] = {OW1, OB1, OG, OBB, ORM, ORV, OW2, OB2, OCH0, OCH1, OCH2, OCH3,
                        OCW1, OCB1, OCG, OCBB, OCRM, OCRV, OCW2, OCB2};
    int a = blockIdx.x;
    int n = SZ[a];
    float* dst = wpad + OF[a];
    if (flag[0] != 0) {
        const u16* s = (const u16*)tab.p[a];
        for (int i = threadIdx.x; i < n; i += 256) dst[i] = bf2f(s[i]);
    } else {
        const float* s = (const float*)tab.p[a];
        for (int i = threadIdx.x; i < n; i += 256) dst[i] = s[i];
    }
}

// Fold PAE BN into W2 (MFMA B-frag swizzled bf16) + b2'.
__global__ __launch_bounds__(128) void k_fold(const float* __restrict__ wpad,
                                              u16* __restrict__ W2s, float* __restrict__ b2p) {
    const float* g = wpad + OG;
    const float* b = wpad + OBB;
    const float* rm = wpad + ORM;
    const float* rv = wpad + ORV;
    const float* w2 = wpad + OW2;
    const float* b2 = wpad + OB2;
    int blk = blockIdx.x, tid = threadIdx.x;
    if (blk < 32) {
        int kc = blk >> 3, jt = blk & 7;
        int lane = tid & 63, jh = tid >> 6;
        for (int jj = 0; jj < 4; jj++) {
            int j = jh * 4 + jj;
            int k = kc * 32 + (lane >> 4) * 8 + j;
            int jcol = jt * 16 + (lane & 15);
            float s = g[k] * rsqrtf(rv[k] + 1e-5f);
            W2s[((kc * 8 + jt) * 64 + lane) * 8 + j] = f2bf(s * w2[k * 128 + jcol]);
        }
    } else {
        if (tid < 128) {
            int j = tid;
            float acc = b2[j];
            for (int k = 0; k < 128; k++) {
                float s = g[k] * rsqrtf(rv[k] + 1e-5f);
                float t = b[k] - rm[k] * s;
                acc += t * w2[k * 128 + j];
            }
            b2p[j] = acc;
        }
    }
}

// features (either dtype) -> bf16 X0.
__global__ __launch_bounds__(256) void k_x0(const void* __restrict__ feat, const int* __restrict__ flag,
                                            u16* __restrict__ X0) {
    int i = blockIdx.x * 256 + threadIdx.x;
    if (flag[0] != 0) {
        ((uint4*)X0)[i] = ((const uint4*)feat)[i];
    } else {
        const float4* f = (const float4*)feat;
        float4 a = f[2 * i], b = f[2 * i + 1];
        u16x8 o;
        o[0] = f2bf(a.x); o[1] = f2bf(a.y); o[2] = f2bf(a.z); o[3] = f2bf(a.w);
        o[4] = f2bf(b.x); o[5] = f2bf(b.y); o[6] = f2bf(b.z); o[7] = f2bf(b.w);
        ((uint4*)X0)[i] = __builtin_bit_cast(uint4, o);
    }
}

// PAE: A = relu(Z@W1+b1) on VALU (fragments staged once), H = A@W2' via MFMA.
// jt loop is NOT unrolled: full unroll hoisted all 32 ds_read B-fragments
// (128 VGPRs) -> 256 VGPR + 113 MB scratch spill (rounds 2 & 4). unroll 1
// caps the in-flight B fragments at 4 (16 VGPRs).
__global__ __launch_bounds__(256) void k_pae(const void* __restrict__ zin, const float* __restrict__ wpad,
                                             const u16* __restrict__ W2sg, const float* __restrict__ b2p,
                                             const int* __restrict__ ei, const int* __restrict__ flag,
                                             float* __restrict__ ewf, void* __restrict__ dout,
                                             float* __restrict__ deg, int* __restrict__ cnt) {
    __shared__ __align__(16) u16 sW2[16384];
    __shared__ float sW1[6 * 128];
    __shared__ float sB1[128];
    __shared__ float sB2[128];
    int tid = threadIdx.x;
    for (int i = tid; i < 8192; i += 256) ((u32*)sW2)[i] = ((const u32*)W2sg)[i];
    for (int i = tid; i < 768; i += 256) sW1[i] = wpad[OW1 + i];
    if (tid < 128) { sB1[tid] = wpad[OB1 + tid]; sB2[tid] = b2p[tid]; }
    __syncthreads();

    bool isbf = flag[0] != 0;
    int wv = __builtin_amdgcn_readfirstlane(tid >> 6);
    int lane = tid & 63;
    int quad = lane >> 4, lrow = lane & 15, jc = lane & 15;
    int gw = blockIdx.x * 4 + wv;
    const int ngroups = EE / 16;

#pragma unroll 1
    for (int gidx = gw; gidx < ngroups; gidx += gridDim.x * 4) {
        int e0 = gidx * 16;
        float z1[6], z2[6];
        if (isbf) {
            const u32* zp = (const u32*)((const u16*)zin + (size_t)(e0 + lrow) * 12);
            u32 u0 = zp[0], u1 = zp[1], u2 = zp[2], u3 = zp[3], u4 = zp[4], u5 = zp[5];
            z1[0] = bfl(u0); z1[1] = bfh(u0); z1[2] = bfl(u1); z1[3] = bfh(u1); z1[4] = bfl(u2); z1[5] = bfh(u2);
            z2[0] = bfl(u3); z2[1] = bfh(u3); z2[2] = bfl(u4); z2[3] = bfh(u4); z2[4] = bfl(u5); z2[5] = bfh(u5);
        } else {
            const float4* zp = (const float4*)((const float*)zin + (size_t)(e0 + lrow) * 12);
            float4 p0 = zp[0], p1 = zp[1], p2 = zp[2];
            z1[0] = p0.x; z1[1] = p0.y; z1[2] = p0.z; z1[3] = p0.w; z1[4] = p1.x; z1[5] = p1.y;
            z2[0] = p1.z; z2[1] = p1.w; z2[2] = p2.x; z2[3] = p2.y; z2[4] = p2.z; z2[5] = p2.w;
        }

        // Stage A fragments for all 4 kc chunks (32 VGPRs total)
        bf16x8 a1f[4], a2f[4];
#pragma unroll
        for (int kc = 0; kc < 4; kc++) {
            u16x8 a1u, a2u;
            int kbase = kc * 32 + quad * 8;
#pragma unroll
            for (int j = 0; j < 8; j++) {
                int k = kbase + j;
                float s1 = sB1[k], s2 = s1;
#pragma unroll
                for (int m = 0; m < 6; m++) {
                    float wm = sW1[m * 128 + k];
                    s1 = fmaf(z1[m], wm, s1);
                    s2 = fmaf(z2[m], wm, s2);
                }
                a1u[j] = f2bf(fmaxf(s1, 0.f));
                a2u[j] = f2bf(fmaxf(s2, 0.f));
            }
            a1f[kc] = __builtin_bit_cast(bf16x8, a1u);
            a2f[kc] = __builtin_bit_cast(bf16x8, a2u);
        }

        float num[4] = {0, 0, 0, 0}, q1[4] = {0, 0, 0, 0}, q2[4] = {0, 0, 0, 0};
        // jt NOT unrolled (see header comment): keeps ds_read hoisting bounded.
#pragma unroll 1
        for (int jt = 0; jt < 8; jt++) {
            f32x4 acc1 = {0.f, 0.f, 0.f, 0.f}, acc2 = {0.f, 0.f, 0.f, 0.f};
#pragma unroll
            for (int kc = 0; kc < 4; kc++) {
                bf16x8 bb = *reinterpret_cast<const bf16x8*>(&sW2[((kc * 8 + jt) * 64 + lane) * 8]);
                acc1 = __builtin_amdgcn_mfma_f32_16x16x32_bf16(a1f[kc], bb, acc1, 0, 0, 0);
                acc2 = __builtin_amdgcn_mfma_f32_16x16x32_bf16(a2f[kc], bb, acc2, 0, 0, 0);
            }
            float bbias = sB2[jt * 16 + jc];
#pragma unroll
            for (int r = 0; r < 4; r++) {
                float h1 = acc1[r] + bbias;
                float h2 = acc2[r] + bbias;
                num[r] = fmaf(h1, h2, num[r]);
                q1[r] = fmaf(h1, h1, q1[r]);
                q2[r] = fmaf(h2, h2, q2[r]);
            }
        }
#pragma unroll
        for (int off = 1; off < 16; off <<= 1) {
#pragma unroll
            for (int r = 0; r < 4; r++) {
                num[r] += __shfl_xor(num[r], off);
                q1[r] += __shfl_xor(q1[r], off);
                q2[r] += __shfl_xor(q2[r], off);
            }
        }
        if (jc == 0) {
#pragma unroll
            for (int r = 0; r < 4; r++) {
                int e = e0 + quad * 4 + r;
                float den = fmaxf(sqrtf(q1[r]) * sqrtf(q2[r]), 1e-8f);
                float wgt = (num[r] / den + 1.f) * 0.5f;
                if (!(wgt == wgt)) wgt = 0.5f;  // NaN guard: makes failures localizable
                ewf[e] = wgt;
                if (isbf) ((u16*)dout)[EW_OFF + e] = f2bf(wgt);
                else ((float*)dout)[EW_OFF + e] = wgt;
                int row = ei[e];
                atomicAdd(deg + row, wgt);
                atomicAdd(cnt + row, 1);
            }
        }
    }
}

// Exclusive scan of cnt -> offs; fused dis = rsqrt(deg).
__global__ __launch_bounds__(1024) void k_scan(const int* __restrict__ cnt, const float* __restrict__ deg,
                                               int* __restrict__ offs, float* __restrict__ dis) {
    __shared__ int wsum[16];
    __shared__ int carry;
    int tid = threadIdx.x;
    int wv = tid >> 6, lane = tid & 63;
    if (tid == 0) carry = 0;
    __syncthreads();
    for (int c = 0; c < 49; c++) {
        int i = c * 1024 + tid;
        int v = (i < NN) ? cnt[i] : 0;
        if (i < NN) {
            float d = deg[i];
            dis[i] = d > 0.f ? rsqrtf(d) : 0.f;
        }
        int x = v;
#pragma unroll
        for (int off = 1; off < 64; off <<= 1) {
            int t = __shfl_up(x, off);
            if (lane >= off) x += t;
        }
        if (lane == 63) wsum[wv] = x;
        __syncthreads();
        if (tid < 16) {
            int s = wsum[tid];
#pragma unroll
            for (int off = 1; off < 16; off <<= 1) {
                int t = __shfl_up(s, off, 16);
                if (tid >= off) s += t;
            }
            wsum[tid] = s;
        }
        __syncthreads();
        int base = carry + (wv > 0 ? wsum[wv - 1] : 0);
        if (i < NN) offs[i] = base + x - v;
        __syncthreads();
        if (tid == 0) carry += wsum[15];
        __syncthreads();
    }
    if (tid == 0) offs[NN] = carry;
}

// CSR scatter: fused (col, norm) uint2 metadata — one 8B load per edge in prop.
__global__ __launch_bounds__(256) void k_csr(const int* __restrict__ ei, const float* __restrict__ ewf,
                                             const float* __restrict__ dis, const int* __restrict__ offs,
                                             int* __restrict__ cursor, uint2* __restrict__ csr_meta) {
    int e = blockIdx.x * 256 + threadIdx.x;
    int r = ei[e], c = ei[EE + e];
    float wgt = ewf[e];
    int pos = offs[r] + atomicAdd(cursor + r, 1);
    float nrm = -dis[r] * wgt * dis[c];
    csr_meta[pos] = make_uint2((u32)c, __builtin_bit_cast(u32, nrm));
}

// Propagation over bf16 node features, fp32 accumulate. One wave per node,
// 16 lanes per edge; 8 edges in flight (2x unrolled) for MLP.
template <int F>
__global__ __launch_bounds__(256) void k_prop(const u16* __restrict__ src, const uint2* __restrict__ csr_meta,
                                              const int* __restrict__ offs,
                                              u16* __restrict__ out, const u16* __restrict__ base,
                                              float alpha, float beta) {
    int lane = threadIdx.x & 63;
    int wv = threadIdx.x >> 6;
    int node = blockIdx.x * 4 + wv;
    int s = offs[node], e = offs[node + 1];
    int sub = lane >> 4;   // which of 4 edges this lane group handles
    int fl = lane & 15;    // position within the feature row

    if (F == 128) {
        const uint4* sv = (const uint4*)src;  // row = 16 uint4 (128 bf16)
        float a[8] = {0, 0, 0, 0, 0, 0, 0, 0};
        int p = s;
        for (; p + 7 < e; p += 8) {
            uint2 m0 = csr_meta[p + sub];
            uint2 m1 = csr_meta[p + 4 + sub];
            uint4 v0 = sv[(size_t)m0.x * 16 + fl];
            uint4 v1 = sv[(size_t)m1.x * 16 + fl];
            float w0 = __builtin_bit_cast(float, m0.y);
            float w1 = __builtin_bit_cast(float, m1.y);
            a[0] = fmaf(w0, bfl(v0.x), a[0]); a[1] = fmaf(w0, bfh(v0.x), a[1]);
            a[2] = fmaf(w0, bfl(v0.y), a[2]); a[3] = fmaf(w0, bfh(v0.y), a[3]);
            a[4] = fmaf(w0, bfl(v0.z), a[4]); a[5] = fmaf(w0, bfh(v0.z), a[5]);
            a[6] = fmaf(w0, bfl(v0.w), a[6]); a[7] = fmaf(w0, bfh(v0.w), a[7]);
            a[0] = fmaf(w1, bfl(v1.x), a[0]); a[1] = fmaf(w1, bfh(v1.x), a[1]);
            a[2] = fmaf(w1, bfl(v1.y), a[2]); a[3] = fmaf(w1, bfh(v1.y), a[3]);
            a[4] = fmaf(w1, bfl(v1.z), a[4]); a[5] = fmaf(w1, bfh(v1.z), a[5]);
            a[6] = fmaf(w1, bfl(v1.w), a[6]); a[7] = fmaf(w1, bfh(v1.w), a[7]);
        }
        if (p + 3 < e) {
            uint2 m0 = csr_meta[p + sub];
            uint4 v0 = sv[(size_t)m0.x * 16 + fl];
            float w0 = __builtin_bit_cast(float, m0.y);
            a[0] = fmaf(w0, bfl(v0.x), a[0]); a[1] = fmaf(w0, bfh(v0.x), a[1]);
            a[2] = fmaf(w0, bfl(v0.y), a[2]); a[3] = fmaf(w0, bfh(v0.y), a[3]);
            a[4] = fmaf(w0, bfl(v0.z), a[4]); a[5] = fmaf(w0, bfh(v0.z), a[5]);
            a[6] = fmaf(w0, bfl(v0.w), a[6]); a[7] = fmaf(w0, bfh(v0.w), a[7]);
            p += 4;
        }
#pragma unroll
        for (int i = 0; i < 8; i++) {
            a[i] += __shfl_xor(a[i], 16);
            a[i] += __shfl_xor(a[i], 32);
        }
        if (sub == 0) {
            for (; p < e; p++) {
                uint2 m0 = csr_meta[p];
                uint4 v = sv[(size_t)m0.x * 16 + fl];
                float w = __builtin_bit_cast(float, m0.y);
                a[0] = fmaf(w, bfl(v.x), a[0]); a[1] = fmaf(w, bfh(v.x), a[1]);
                a[2] = fmaf(w, bfl(v.y), a[2]); a[3] = fmaf(w, bfh(v.y), a[3]);
                a[4] = fmaf(w, bfl(v.z), a[4]); a[5] = fmaf(w, bfh(v.z), a[5]);
                a[6] = fmaf(w, bfl(v.w), a[6]); a[7] = fmaf(w, bfh(v.w), a[7]);
            }
            float o[8];
#pragma unroll
            for (int i = 0; i < 8; i++) o[i] = alpha * a[i];
            if (beta != 0.f) {
                uint4 bv = ((const uint4*)base)[(size_t)node * 16 + fl];
                o[0] = fmaf(beta, bfl(bv.x), o[0]); o[1] = fmaf(beta, bfh(bv.x), o[1]);
                o[2] = fmaf(beta, bfl(bv.y), o[2]); o[3] = fmaf(beta, bfh(bv.y), o[3]);
                o[4] = fmaf(beta, bfl(bv.z), o[4]); o[5] = fmaf(beta, bfh(bv.z), o[5]);
                o[6] = fmaf(beta, bfl(bv.w), o[6]); o[7] = fmaf(beta, bfh(bv.w), o[7]);
            }
            uint4 ov;
            ov.x = (u32)f2bf(o[0]) | ((u32)f2bf(o[1]) << 16);
            ov.y = (u32)f2bf(o[2]) | ((u32)f2bf(o[3]) << 16);
            ov.z = (u32)f2bf(o[4]) | ((u32)f2bf(o[5]) << 16);
            ov.w = (u32)f2bf(o[6]) | ((u32)f2bf(o[7]) << 16);
            ((uint4*)out)[(size_t)node * 16 + fl] = ov;
        }
    } else {
        const uint2* sv = (const uint2*)src;  // row = 16 uint2 (64 bf16)
        float a[4] = {0, 0, 0, 0};
        int p = s;
        for (; p + 7 < e; p += 8) {
            uint2 m0 = csr_meta[p + sub];
            uint2 m1 = csr_meta[p + 4 + sub];
            uint2 v0 = sv[(size_t)m0.x * 16 + fl];
            uint2 v1 = sv[(size_t)m1.x * 16 + fl];
            float w0 = __builtin_bit_cast(float, m0.y);
            float w1 = __builtin_bit_cast(float, m1.y);
            a[0] = fmaf(w0, bfl(v0.x), a[0]); a[1] = fmaf(w0, bfh(v0.x), a[1]);
            a[2] = fmaf(w0, bfl(v0.y), a[2]); a[3] = fmaf(w0, bfh(v0.y), a[3]);
            a[0] = fmaf(w1, bfl(v1.x), a[0]); a[1] = fmaf(w1, bfh(v1.x), a[1]);
            a[2] = fmaf(w1, bfl(v1.y), a[2]); a[3] = fmaf(w1, bfh(v1.y), a[3]);
        }
        if (p + 3 < e) {
            uint2 m0 = csr_meta[p + sub];
            uint2 v0 = sv[(size_t)m0.x * 16 + fl];
            float w0 = __builtin_bit_cast(float, m0.y);
            a[0] = fmaf(w0, bfl(v0.x), a[0]); a[1] = fmaf(w0, bfh(v0.x), a[1]);
            a[2] = fmaf(w0, bfl(v0.y), a[2]); a[3] = fmaf(w0, bfh(v0.y), a[3]);
            p += 4;
        }
#pragma unroll
        for (int i = 0; i < 4; i++) {
            a[i] += __shfl_xor(a[i], 16);
            a[i] += __shfl_xor(a[i], 32);
        }
        if (sub == 0) {
            for (; p < e; p++) {
                uint2 m0 = csr_meta[p];
                uint2 v = sv[(size_t)m0.x * 16 + fl];
                float w = __builtin_bit_cast(float, m0.y);
                a[0] = fmaf(w, bfl(v.x), a[0]); a[1] = fmaf(w, bfh(v.x), a[1]);
                a[2] = fmaf(w, bfl(v.y), a[2]); a[3] = fmaf(w, bfh(v.y), a[3]);
            }
            float o[4];
#pragma unroll
            for (int i = 0; i < 4; i++) o[i] = alpha * a[i];
            if (beta != 0.f) {
                uint2 bv = ((const uint2*)base)[(size_t)node * 16 + fl];
                o[0] = fmaf(beta, bfl(bv.x), o[0]); o[1] = fmaf(beta, bfh(bv.x), o[1]);
                o[2] = fmaf(beta, bfl(bv.y), o[2]); o[3] = fmaf(beta, bfh(bv.y), o[3]);
            }
            uint2 ov;
            ov.x = (u32)f2bf(o[0]) | ((u32)f2bf(o[1]) << 16);
            ov.y = (u32)f2bf(o[2]) | ((u32)f2bf(o[3]) << 16);
            ((uint2*)out)[(size_t)node * 16 + fl] = ov;
        }
    }
}

// ChebConv mix -> bf16 h + jk slice (out dtype).
template <int F>
__global__ __launch_bounds__(256) void k_gemm(const u16* __restrict__ X0, const u16* __restrict__ X1,
                                              const u16* __restrict__ X2, const float* __restrict__ Wg,
                                              u16* __restrict__ Hout, void* __restrict__ jk, int jkoff,
                                              const int* __restrict__ flag) {
    __shared__ u16 sW[3 * 64 * (F + 4)];
    int tid = threadIdx.x;
    for (int idx = tid; idx < 3 * F * 64; idx += 256) {
        int j = idx & 63;
        int rest = idx >> 6;
        int k = rest % F;
        int p = rest / F;
        sW[(p * 64 + j) * (F + 4) + k] = f2bf(Wg[(p * F + k) * 64 + j]);
    }
    __syncthreads();
    bool isbf = flag[0] != 0;
    int wv = __builtin_amdgcn_readfirstlane(tid >> 6);
    int lane = tid & 63;
    int nbase = blockIdx.x * 32 + wv * 8;
    float acc[8] = {0, 0, 0, 0, 0, 0, 0, 0};
    const u16* Xs[3] = {X0, X1, X2};
    for (int p = 0; p < 3; p++) {
        const u16* Xp = Xs[p];
        const u16* wrow = &sW[(p * 64 + lane) * (F + 4)];
        const u16* rp[8];
#pragma unroll
        for (int i = 0; i < 8; i++) {
            int n = nbase + i;
            if (n > NN - 1) n = NN - 1;
            rp[i] = Xp + (size_t)n * F;
        }
        for (int k = 0; k < F; k += 4) {
            U16x4 w4 = *(const U16x4*)&wrow[k];
            float w0 = bf2f(w4.a), w1 = bf2f(w4.b), w2 = bf2f(w4.c), w3 = bf2f(w4.d);
#pragma unroll
            for (int i = 0; i < 8; i++) {
                U16x4 xv = *(const U16x4*)(rp[i] + k);
                acc[i] = fmaf(bf2f(xv.a), w0, acc[i]);
                acc[i] = fmaf(bf2f(xv.b), w1, acc[i]);
                acc[i] = fmaf(bf2f(xv.c), w2, acc[i]);
                acc[i] = fmaf(bf2f(xv.d), w3, acc[i]);
            }
        }
    }
#pragma unroll
    for (int i = 0; i < 8; i++) {
        int n = nbase + i;
        if (n < NN) {
            float v = fmaxf(acc[i], 0.f);
            Hout[(size_t)n * 64 + lane] = f2bf(v);
            if (isbf) ((u16*)jk)[(size_t)n * 256 + jkoff + lane] = f2bf(v);
            else ((float*)jk)[(size_t)n * 256 + jkoff + lane] = v;
        }
    }
}

// Classifier stage 1 -> internal bf16 z.
__global__ __launch_bounds__(256) void k_cls1(const u16* __restrict__ h0, const u16* __restrict__ h1,
                                              const u16* __restrict__ h2, const u16* __restrict__ h3,
                                              const float* __restrict__ wpad, u16* __restrict__ zout) {
    __shared__ u16 sW[64 * 260];
    int tid = threadIdx.x;
    int jch = blockIdx.y;
    const float* w1 = wpad + OCW1;
    for (int idx = tid; idx < 64 * 256; idx += 256) {
        int j = idx & 63, k = idx >> 6;
        sW[j * 260 + k] = f2bf(w1[k * 256 + jch * 64 + j]);
    }
    __syncthreads();
    int wv = __builtin_amdgcn_readfirstlane(tid >> 6);
    int lane = tid & 63;
    int nbase = blockIdx.x * 32 + wv * 8;
    float acc[8] = {0, 0, 0, 0, 0, 0, 0, 0};
    const u16* hs[4] = {h0, h1, h2, h3};
    const u16* wrow = &sW[lane * 260];
    for (int l = 0; l < 4; l++) {
        const u16* hb = hs[l];
        const u16* rp[8];
#pragma unroll
        for (int i = 0; i < 8; i++) {
            int n = nbase + i;
            if (n > NN - 1) n = NN - 1;
            rp[i] = hb + (size_t)n * 64;
        }
        for (int kk = 0; kk < 64; kk += 4) {
            U16x4 w4 = *(const U16x4*)&wrow[l * 64 + kk];
            float w0 = bf2f(w4.a), w1f = bf2f(w4.b), w2f = bf2f(w4.c), w3f = bf2f(w4.d);
#pragma unroll
            for (int i = 0; i < 8; i++) {
                U16x4 xv = *(const U16x4*)(rp[i] + kk);
                acc[i] = fmaf(bf2f(xv.a), w0, acc[i]);
                acc[i] = fmaf(bf2f(xv.b), w1f, acc[i]);
                acc[i] = fmaf(bf2f(xv.c), w2f, acc[i]);
                acc[i] = fmaf(bf2f(xv.d), w3f, acc[i]);
            }
        }
    }
    int j = jch * 64 + lane;
    float bb1 = wpad[OCB1 + j];
    float s = wpad[OCG + j] * rsqrtf(wpad[OCRV + j] + 1e-5f);
    float t = wpad[OCBB + j] - wpad[OCRM + j] * s;
#pragma unroll
    for (int i = 0; i < 8; i++) {
        int n = nbase + i;
        if (n < NN) {
            float v = fmaxf(acc[i] + bb1, 0.f) * s + t;
            zout[(size_t)n * 256 + j] = f2bf(v);
        }
    }
}

// Classifier stage 2: logit into d_out at LG_OFF (out dtype).
__global__ __launch_bounds__(256) void k_cls2(const u16* __restrict__ z, const float* __restrict__ wpad,
                                              const int* __restrict__ flag, void* __restrict__ dout) {
    __shared__ float sw2[512];
    __shared__ float sb2[2];
    int tid = threadIdx.x;
    for (int i = tid; i < 512; i += 256) sw2[i] = wpad[OCW2 + i];
    if (tid < 2) sb2[tid] = wpad[OCB2 + tid];
    __syncthreads();
    bool isbf = flag[0] != 0;
    int wv = __builtin_amdgcn_readfirstlane(tid >> 6);
    int lane = tid & 63;
    int node = blockIdx.x * 4 + wv;
    U16x4 zv = *(const U16x4*)(z + (size_t)node * 256 + lane * 4);
    float zf[4] = {bf2f(zv.a), bf2f(zv.b), bf2f(zv.c), bf2f(zv.d)};
    float p0 = 0.f, p1 = 0.f;
#pragma unroll
    for (int m = 0; m < 4; m++) {
        int k = lane * 4 + m;
        p0 = fmaf(zf[m], sw2[k * 2 + 0], p0);
        p1 = fmaf(zf[m], sw2[k * 2 + 1], p1);
    }
#pragma unroll
    for (int off = 1; off < 64; off <<= 1) {
        p0 += __shfl_xor(p0, off);
        p1 += __shfl_xor(p1, off);
    }
    if (lane == 0) {
        float l0 = p0 + sb2[0], l1 = p1 + sb2[1];
        if (isbf) {
            u32 pack = (u32)f2bf(l0) | ((u32)f2bf(l1) << 16);
            *(u32*)((u16*)dout + LG_OFF + (size_t)node * 2) = pack;
        } else {
            float2 o = {l0, l1};
            *(float2*)((float*)dout + LG_OFF + (size_t)node * 2) = o;
        }
    }
}

extern "C" void kernel_launch(void* const* d_in, const int* in_sizes, int n_in,
                              void* d_out, int out_size, void* d_ws, size_t ws_size,
                              hipStream_t stream) {
    const void* features = d_in[0];
    const int* ei = (const int*)d_in[1];
    const void* zin = d_in[2];

    char* w = (char*)d_ws;
    auto alloc = [&](size_t bytes) -> void* {
        void* p = (void*)w;
        w += (bytes + 255) & ~(size_t)255;
        return p;
    };
    u16* X0 = (u16*)alloc((size_t)NN * 128 * 2);
    u16* Tx1 = (u16*)alloc((size_t)NN * 128 * 2);
    u16* Tx2 = (u16*)alloc((size_t)NN * 128 * 2);
    u16* h0 = (u16*)alloc((size_t)NN * 64 * 2);
    u16* h1 = (u16*)alloc((size_t)NN * 64 * 2);
    u16* h2 = (u16*)alloc((size_t)NN * 64 * 2);
    u16* h3 = (u16*)alloc((size_t)NN * 64 * 2);
    float* ewf = (float*)alloc((size_t)EE * 4);
    uint2* csr_meta = (uint2*)alloc((size_t)EE * 8);
    float* deg = (float*)alloc((size_t)NN * 4);
    int* cnt = (int*)alloc((size_t)NN * 4);
    int* cursor = (int*)alloc((size_t)NN * 4);
    float* dis = (float*)alloc((size_t)NN * 4);
    int* offs = (int*)alloc((size_t)(NN + 1) * 4);
    u16* W2s = (u16*)alloc((size_t)16384 * 2);
    float* b2p = (float*)alloc((size_t)128 * 4);
    float* wpad = (float*)alloc((size_t)OTOT * 4);
    int* flag = (int*)alloc(256);
    u16* z = X0;  // reuses X0+Tx1 region (25.6MB), free after layer-3 gemm

    hipMemsetAsync(deg, 0, (size_t)((char*)dis - (char*)deg), stream);

    PtrTab tab;
    for (int i = 0; i < 20; i++) tab.p[i] = d_in[3 + i];

    k_detect<<<1, 256, 0, stream>>>((const u16*)features, flag);
    k_wconv<<<20, 256, 0, stream>>>(tab, flag, wpad);
    k_fold<<<33, 128, 0, stream>>>(wpad, W2s, b2p);
    k_x0<<<3125, 256, 0, stream>>>(features, flag, X0);
    k_pae<<<1024, 256, 0, stream>>>(zin, wpad, W2s, b2p, ei, flag, ewf, d_out, deg, cnt);
    k_scan<<<1, 1024, 0, stream>>>(cnt, deg, offs, dis);
    k_csr<<<EE / 256, 256, 0, stream>>>(ei, ewf, dis, offs, cursor, csr_meta);

    // layer 0 (F=128)
    k_prop<128><<<12500, 256, 0, stream>>>(X0, csr_meta, offs, Tx1, nullptr, 1.f, 0.f);
    k_prop<128><<<12500, 256, 0, stream>>>(Tx1, csr_meta, offs, Tx2, X0, 2.f, -1.f);
    k_gemm<128><<<1563, 256, 0, stream>>>(X0, Tx1, Tx2, wpad + OCH0, h0, d_out, 0, flag);
    // layer 1 (F=64)
    k_prop<64><<<12500, 256, 0, stream>>>(h0, csr_meta, offs, Tx1, nullptr, 1.f, 0.f);
    k_prop<64><<<12500, 256, 0, stream>>>(Tx1, csr_meta, offs, Tx2, h0, 2.f, -1.f);
    k_gemm<64><<<1563, 256, 0, stream>>>(h0, Tx1, Tx2, wpad + OCH1, h1, d_out, 64, flag);
    // layer 2
    k_prop<64><<<12500, 256, 0, stream>>>(h1, csr_meta, offs, Tx1, nullptr, 1.f, 0.f);
    k_prop<64><<<12500, 256, 0, stream>>>(Tx1, csr_meta, offs, Tx2, h1, 2.f, -1.f);
    k_gemm<64><<<1563, 256, 0, stream>>>(h1, Tx1, Tx2, wpad + OCH2, h2, d_out, 128, flag);
    // layer 3
    k_prop<64><<<12500, 256, 0, stream>>>(h2, csr_meta, offs, Tx1, nullptr, 1.f, 0.f);
    k_prop<64><<<12500, 256, 0, stream>>>(Tx1, csr_meta, offs, Tx2, h2, 2.f, -1.f);
    k_gemm<64><<<1563, 256, 0, stream>>>(h2, Tx1, Tx2, wpad + OCH3, h3, d_out, 192, flag);

    // classifier
    k_cls1<<<dim3(1563, 4), 256, 0, stream>>>(h0, h1, h2, h3, wpad, z);
    k_cls2<<<12500, 256, 0, stream>>>(z, wpad, flag, d_out);
    (void)in_sizes; (void)n_in; (void)out_size; (void)ws_size;
}